// Round 10
// baseline (315.450 us; speedup 1.0000x reference)
//
#include <hip/hip_runtime.h>
#include <math.h>

// Problem constants (from reference)
#define BATCH 4
#define HW 512
#define NPLANE (512 * 512)
#define NS 12288      // oversampled points per batch
#define NU 3072       // top-k uncertain selected
#define NR 1024       // random extra points
#define NP 4096       // total selected points per batch
#define CF_CH 64
#define CC_CH 128
#define CIN 192
#define HID 256
#define OUTC 4
#define M_TOT (BATCH * NP)  // 16384
#define GCH_SPLIT 4         // point-chunks per (batch, channel) in gather

typedef __attribute__((ext_vector_type(8))) short bf16x8;
typedef __attribute__((ext_vector_type(4))) float f32x4;

__device__ __forceinline__ unsigned short f32_to_bf16_rne(float f) {
  unsigned u = __float_as_uint(f);
  unsigned r = u + 0x7FFFu + ((u >> 16) & 1u);
  return (unsigned short)(r >> 16);
}
__device__ __forceinline__ float bf16_to_f32(unsigned short h) {
  return __uint_as_float((unsigned)h << 16);
}

// ---------------------------------------------------------------------------
// Bit-exact replication of XLA:CPU's vectorized f32 expf (Cephes polynomial),
// strict per-op f32 rounding, no FMA. DO NOT TOUCH — top-k order depends on it.
// ---------------------------------------------------------------------------
__device__ __forceinline__ float xla_expf(float xin) {
  float x = fminf(fmaxf(xin, -88.3762626647949f), 88.3762626647950f);
  float fx = floorf(__fadd_rn(__fmul_rn(x, 1.44269504088896341f), 0.5f));
  float tmp = __fmul_rn(0.693359375f, fx);
  float z = __fmul_rn(-2.12194440e-4f, fx);
  x = __fsub_rn(__fsub_rn(x, tmp), z);
  float y = __fadd_rn(__fmul_rn(x, 1.9875691500E-4f), 1.3981999507E-3f);
  y = __fadd_rn(__fmul_rn(y, x), 8.3334519073E-3f);
  y = __fadd_rn(__fmul_rn(y, x), 4.1665795894E-2f);
  y = __fadd_rn(__fmul_rn(y, x), 1.6666665459E-1f);
  y = __fadd_rn(__fmul_rn(y, x), 5.0000001201E-1f);
  z = __fmul_rn(x, x);
  y = __fadd_rn(__fmul_rn(y, z), x);
  y = __fadd_rn(y, 1.0f);
  int n = (int)fx;
  float p2n = __int_as_float((n + 127) << 23);
  return __fmul_rn(y, p2n);
}

// ---------------------------------------------------------------------------
// K1: uncertainty at oversampled points (R2/R6-verified, byte-identical).
// ---------------------------------------------------------------------------
__global__ void k_uncert(const float* __restrict__ logits,
                         const float* __restrict__ rp,
                         float* __restrict__ u) {
  int gid = blockIdx.x * 256 + threadIdx.x;
  if (gid >= BATCH * NS) return;
  int b = gid / NS;
  float px = rp[(size_t)gid * 2 + 0];
  float py = rp[(size_t)gid * 2 + 1];
  const float* plane = logits + (size_t)b * OUTC * NPLANE;  // channel 0

  float x = __fsub_rn(__fmul_rn(px, 512.0f), 0.5f);
  float y = __fsub_rn(__fmul_rn(py, 512.0f), 0.5f);
  float x0f = floorf(x), y0f = floorf(y);
  float wx = __fsub_rn(x, x0f);
  float wy = __fsub_rn(y, y0f);
  int x0 = (int)x0f, y0 = (int)y0f;
  int x1 = x0 + 1, y1 = y0 + 1;
  bool vx0 = (x0 >= 0) & (x0 < HW);
  bool vx1 = (x1 >= 0) & (x1 < HW);
  bool vy0 = (y0 >= 0) & (y0 < HW);
  bool vy1 = (y1 >= 0) & (y1 < HW);
  float g00 = (vx0 && vy0) ? plane[y0 * HW + x0] : 0.0f;
  float g10 = (vx1 && vy0) ? plane[y0 * HW + x1] : 0.0f;
  float g01 = (vx0 && vy1) ? plane[y1 * HW + x0] : 0.0f;
  float g11 = (vx1 && vy1) ? plane[y1 * HW + x1] : 0.0f;
  float omx = __fsub_rn(1.0f, wx);
  float omy = __fsub_rn(1.0f, wy);
  float w00 = __fmul_rn(omx, omy);
  float w10 = __fmul_rn(wx, omy);
  float w01 = __fmul_rn(omx, wy);
  float w11 = __fmul_rn(wx, wy);
  float s = __fadd_rn(
      __fadd_rn(__fadd_rn(__fmul_rn(g00, w00), __fmul_rn(g10, w10)),
                __fmul_rn(g01, w01)),
      __fmul_rn(g11, w11));
  float e = xla_expf(-s);
  float sig = __fdiv_rn(1.0f, __fadd_rn(1.0f, e));
  float t = __fmul_rn(fabsf(__fsub_rn(sig, 0.5f)), 2.0f);
  u[gid] = __fsub_rn(1.0f, t);
}

// ---------------------------------------------------------------------------
// K2: exact stable top-k via ranking (R6-verified, byte-identical). CLOSED.
// ---------------------------------------------------------------------------
__global__ __launch_bounds__(256) void k_select(const float* __restrict__ u,
                                                const float* __restrict__ rp,
                                                float* __restrict__ pts_out) {
  __shared__ __align__(16) float su[NS];
  int b = blockIdx.x / (NS / 256);
  int blk = blockIdx.x % (NS / 256);
  const float* ub = u + (size_t)b * NS;
  for (int t = threadIdx.x; t < NS / 4; t += 256)
    ((float4*)su)[t] = ((const float4*)ub)[t];
  __syncthreads();
  int i = blk * 256 + (int)threadIdx.x;
  int wb = i & ~63;  // wave-uniform (blk*256 is 64-aligned)
  float ui = su[i];
  int r0 = 0, r1 = 0, r2 = 0, r3 = 0;
  for (int j = 0; j < wb; j += 8) {
    float4 v = *(const float4*)&su[j];
    float4 w = *(const float4*)&su[j + 4];
    r0 += (v.x >= ui) + (w.x >= ui);
    r1 += (v.y >= ui) + (w.y >= ui);
    r2 += (v.z >= ui) + (w.z >= ui);
    r3 += (v.w >= ui) + (w.w >= ui);
  }
  for (int j = wb; j < wb + 64; ++j) {
    float vj = su[j];
    r0 += (vj > ui) || (vj == ui && j < i);
  }
  for (int j = wb + 64; j < NS; j += 8) {
    float4 v = *(const float4*)&su[j];
    float4 w = *(const float4*)&su[j + 4];
    r0 += (v.x > ui) + (w.x > ui);
    r1 += (v.y > ui) + (w.y > ui);
    r2 += (v.z > ui) + (w.z > ui);
    r3 += (v.w > ui) + (w.w > ui);
  }
  int rank = (r0 + r1) + (r2 + r3);
  if (rank < NU) {
    pts_out[((size_t)b * NP + rank) * 2 + 0] = rp[((size_t)b * NS + i) * 2 + 0];
    pts_out[((size_t)b * NP + rank) * 2 + 1] = rp[((size_t)b * NS + i) * 2 + 1];
  }
}

// K2b: append the random-extra points (byte-identical).
__global__ void k_extra(const float* __restrict__ re, float* __restrict__ pts_out) {
  int gid = blockIdx.x * 256 + threadIdx.x;
  if (gid >= BATCH * NR) return;
  int b = gid / NR, j = gid % NR;
  pts_out[((size_t)b * NP + NU + j) * 2 + 0] = re[(size_t)gid * 2 + 0];
  pts_out[((size_t)b * NP + NU + j) * 2 + 1] = re[(size_t)gid * 2 + 1];
}

// ---------------------------------------------------------------------------
// K3a: per-point bilinear metadata (byte-identical).
// ---------------------------------------------------------------------------
__global__ void k_prep(const float* __restrict__ pts, int2* __restrict__ m2,
                       float4* __restrict__ wts) {
  int g = blockIdx.x * 256 + threadIdx.x;
  if (g >= M_TOT) return;
  float px = pts[(size_t)g * 2 + 0];
  float py = pts[(size_t)g * 2 + 1];
  float x = px * 512.0f - 0.5f;
  float y = py * 512.0f - 0.5f;
  float x0f = floorf(x), y0f = floorf(y);
  float wx = x - x0f, wy = y - y0f;
  int x0 = (int)x0f, y0 = (int)y0f;
  bool vx0 = (unsigned)x0 < (unsigned)HW;
  bool vx1 = (unsigned)(x0 + 1) < (unsigned)HW;
  bool vy0 = (unsigned)y0 < (unsigned)HW;
  bool vy1 = (unsigned)(y0 + 1) < (unsigned)HW;
  int vm = (int)(vx0 && vy0) | ((int)(vx1 && vy0) << 1) |
           ((int)(vx0 && vy1) << 2) | ((int)(vx1 && vy1) << 3);
  m2[g] = make_int2(y0 * HW + x0, vm);
  wts[g] = make_float4((1.0f - wx) * (1.0f - wy), wx * (1.0f - wy),
                       (1.0f - wx) * wy, wx * wy);
}

// ---------------------------------------------------------------------------
// K3b: counting-sort by row (byte-identical, R9-verified).
// ---------------------------------------------------------------------------
__global__ __launch_bounds__(512) void k_sort(const int2* __restrict__ m2,
                                              int* __restrict__ perm) {
  __shared__ int hist[512], pref[512];
  int b = blockIdx.x, tid = threadIdx.x;
  hist[tid] = 0;
  __syncthreads();
  for (int p = tid; p < NP; p += 512) {
    int i00 = m2[(size_t)b * NP + p].x;
    int key = min(max(i00, 0), NPLANE - 1) >> 9;
    atomicAdd(&hist[key], 1);
  }
  __syncthreads();
  int v = hist[tid];
  pref[tid] = v;
  __syncthreads();
  for (int d = 1; d < 512; d <<= 1) {
    int t = (tid >= d) ? pref[tid - d] : 0;
    __syncthreads();
    pref[tid] += t;
    __syncthreads();
  }
  hist[tid] = pref[tid] - v;
  __syncthreads();
  for (int p = tid; p < NP; p += 512) {
    int i00 = m2[(size_t)b * NP + p].x;
    int key = min(max(i00, 0), NPLANE - 1) >> 9;
    int pos = atomicAdd(&hist[key], 1);
    perm[(size_t)b * NP + pos] = p;
  }
}

// ---------------------------------------------------------------------------
// K3c: materialize metadata in sorted order (byte-identical).
// ---------------------------------------------------------------------------
__global__ void k_reorder(const int* __restrict__ perm,
                          const int2* __restrict__ m2,
                          const float4* __restrict__ wts,
                          int2* __restrict__ m2s, float4* __restrict__ wtss) {
  int gid = blockIdx.x * 256 + threadIdx.x;
  if (gid >= M_TOT) return;
  int b = gid / NP;
  int p = perm[gid];
  m2s[gid] = m2[(size_t)b * NP + p];
  wtss[gid] = wts[(size_t)b * NP + p];
}

// ---------------------------------------------------------------------------
// K3d: gather in sorted point order (byte-identical, R9-verified).
// featsT[c][b*NP + s] with s in sorted space.
// ---------------------------------------------------------------------------
__global__ __launch_bounds__(256) void k_gather5(
    const float* __restrict__ fine, const float* __restrict__ coarse,
    const int2* __restrict__ m2s, const float4* __restrict__ wtss,
    float* __restrict__ featsT) {
  int c = blockIdx.x % CIN;
  int rem = blockIdx.x / CIN;
  int b = rem & (BATCH - 1);
  int part = rem >> 2;
  const float* plane = (c < CF_CH)
                           ? fine + ((size_t)b * CF_CH + c) * NPLANE
                           : coarse + ((size_t)b * CC_CH + (c - CF_CH)) * NPLANE;
  const int2* m2b = m2s + (size_t)b * NP;
  const float4* wtsb = wtss + (size_t)b * NP;
  float* outrow = featsT + (size_t)c * M_TOT + (size_t)b * NP;
  int s0 = part * (NP / GCH_SPLIT);
#pragma unroll
  for (int q = 0; q < NP / GCH_SPLIT / 256; ++q) {
    int s = s0 + q * 256 + (int)threadIdx.x;
    int2 mm = m2b[s];
    float4 w = wtsb[s];
    const float* bp = plane + mm.x;
    float t00 = 0.0f, t10 = 0.0f, t01 = 0.0f, t11 = 0.0f;
    if (mm.y & 1) t00 = bp[0] * w.x;
    if (mm.y & 2) t10 = bp[1] * w.y;
    if (mm.y & 4) t01 = bp[HW] * w.z;
    if (mm.y & 8) t11 = bp[HW + 1] * w.w;
    outrow[s] = ((t00 + t10) + t01) + t11;
  }
}

// ---------------------------------------------------------------------------
// K4a: transpose + split-convert feats: featsT f32 [CIN][M] -> AH/AL bf16
// [M][CIN] (hi = bf16(x), lo = bf16(x - hi)). LDS 32x64 tile.
// ---------------------------------------------------------------------------
__global__ __launch_bounds__(256) void k_convA(const float* __restrict__ featsT,
                                               unsigned short* __restrict__ AH,
                                               unsigned short* __restrict__ AL) {
  __shared__ float t[32][65];
  int c0 = (blockIdx.x % (CIN / 32)) * 32;
  int m0 = (blockIdx.x / (CIN / 32)) * 64;
#pragma unroll
  for (int it = 0; it < 8; ++it) {
    int idx = it * 256 + (int)threadIdx.x;
    int cl = idx >> 6, ml = idx & 63;
    t[cl][ml] = featsT[(size_t)(c0 + cl) * M_TOT + m0 + ml];
  }
  __syncthreads();
#pragma unroll
  for (int it = 0; it < 8; ++it) {
    int idx = it * 256 + (int)threadIdx.x;
    int ml = idx >> 5, cl = idx & 31;
    float f = t[cl][ml];
    unsigned short h = f32_to_bf16_rne(f);
    unsigned short l = f32_to_bf16_rne(f - bf16_to_f32(h));
    AH[(size_t)(m0 + ml) * CIN + c0 + cl] = h;
    AL[(size_t)(m0 + ml) * CIN + c0 + cl] = l;
  }
}

// K4b: elementwise split-convert for weights (layout preserved).
__global__ void k_convW(const float* __restrict__ W,
                        unsigned short* __restrict__ WH,
                        unsigned short* __restrict__ WL, int n) {
  int g = blockIdx.x * 256 + threadIdx.x;
  if (g >= n) return;
  float f = W[g];
  unsigned short h = f32_to_bf16_rne(f);
  WH[g] = h;
  WL[g] = f32_to_bf16_rne(f - bf16_to_f32(h));
}

// ---------------------------------------------------------------------------
// K5: split-bf16 MFMA GEMM: C[M][256] = relu(A[M][K] @ B[256][K]^T + bias),
// computed as AhBh + AhBl + AlBh (f32 accum). 64x64 C-tile per block, 4 waves
// each 32x32 (2x2 fragments of mfma_f32_16x16x32_bf16). No LDS: frags are
// 16B-contiguous global loads (A/B stored [row][k] bf16).
// A-frag: row = lane&15, k = kc + (lane>>4)*8 + j  (j-permutation cancels
// between A and B). C/D: col = lane&15, row = (lane>>4)*4 + reg [HW-verified].
// SPLIT=true: epilogue emits bf16 hi/lo pair (next layer's A); else f32.
// ---------------------------------------------------------------------------
template <int K, bool SPLIT>
__global__ __launch_bounds__(256) void k_mfma(
    const unsigned short* __restrict__ AH, const unsigned short* __restrict__ AL,
    const unsigned short* __restrict__ BH, const unsigned short* __restrict__ BL,
    const float* __restrict__ bias, float* __restrict__ outF,
    unsigned short* __restrict__ outH, unsigned short* __restrict__ outL) {
  int lane = (int)threadIdx.x & 63, w = (int)threadIdx.x >> 6;
  int m0 = blockIdx.y * 64 + (w >> 1) * 32;
  int n0 = blockIdx.x * 64 + (w & 1) * 32;
  int rA = lane & 15, kg = (lane >> 4) * 8;
  f32x4 acc00 = {}, acc01 = {}, acc10 = {}, acc11 = {};
  for (int kc = 0; kc < K; kc += 32) {
    int k = kc + kg;
    bf16x8 ah0 = *(const bf16x8*)&AH[(size_t)(m0 + rA) * K + k];
    bf16x8 ah1 = *(const bf16x8*)&AH[(size_t)(m0 + 16 + rA) * K + k];
    bf16x8 al0 = *(const bf16x8*)&AL[(size_t)(m0 + rA) * K + k];
    bf16x8 al1 = *(const bf16x8*)&AL[(size_t)(m0 + 16 + rA) * K + k];
    bf16x8 bh0 = *(const bf16x8*)&BH[(size_t)(n0 + rA) * K + k];
    bf16x8 bh1 = *(const bf16x8*)&BH[(size_t)(n0 + 16 + rA) * K + k];
    bf16x8 bl0 = *(const bf16x8*)&BL[(size_t)(n0 + rA) * K + k];
    bf16x8 bl1 = *(const bf16x8*)&BL[(size_t)(n0 + 16 + rA) * K + k];
    acc00 = __builtin_amdgcn_mfma_f32_16x16x32_bf16(ah0, bh0, acc00, 0, 0, 0);
    acc00 = __builtin_amdgcn_mfma_f32_16x16x32_bf16(ah0, bl0, acc00, 0, 0, 0);
    acc00 = __builtin_amdgcn_mfma_f32_16x16x32_bf16(al0, bh0, acc00, 0, 0, 0);
    acc01 = __builtin_amdgcn_mfma_f32_16x16x32_bf16(ah0, bh1, acc01, 0, 0, 0);
    acc01 = __builtin_amdgcn_mfma_f32_16x16x32_bf16(ah0, bl1, acc01, 0, 0, 0);
    acc01 = __builtin_amdgcn_mfma_f32_16x16x32_bf16(al0, bh1, acc01, 0, 0, 0);
    acc10 = __builtin_amdgcn_mfma_f32_16x16x32_bf16(ah1, bh0, acc10, 0, 0, 0);
    acc10 = __builtin_amdgcn_mfma_f32_16x16x32_bf16(ah1, bl0, acc10, 0, 0, 0);
    acc10 = __builtin_amdgcn_mfma_f32_16x16x32_bf16(al1, bh0, acc10, 0, 0, 0);
    acc11 = __builtin_amdgcn_mfma_f32_16x16x32_bf16(ah1, bh1, acc11, 0, 0, 0);
    acc11 = __builtin_amdgcn_mfma_f32_16x16x32_bf16(ah1, bl1, acc11, 0, 0, 0);
    acc11 = __builtin_amdgcn_mfma_f32_16x16x32_bf16(al1, bh1, acc11, 0, 0, 0);
  }
  int cr = (lane >> 4) * 4;  // fragment row base
  int cc = lane & 15;        // fragment col
  float b0 = bias[n0 + cc], b1v = bias[n0 + 16 + cc];
#pragma unroll
  for (int r = 0; r < 4; ++r) {
#pragma unroll
    for (int fi = 0; fi < 2; ++fi) {
      int row = m0 + fi * 16 + cr + r;
      float v0 = fmaxf((fi ? acc10[r] : acc00[r]) + b0, 0.0f);
      float v1 = fmaxf((fi ? acc11[r] : acc01[r]) + b1v, 0.0f);
      if constexpr (SPLIT) {
        unsigned short h0 = f32_to_bf16_rne(v0);
        unsigned short h1 = f32_to_bf16_rne(v1);
        outH[(size_t)row * HID + n0 + cc] = h0;
        outH[(size_t)row * HID + n0 + 16 + cc] = h1;
        outL[(size_t)row * HID + n0 + cc] = f32_to_bf16_rne(v0 - bf16_to_f32(h0));
        outL[(size_t)row * HID + n0 + 16 + cc] =
            f32_to_bf16_rne(v1 - bf16_to_f32(h1));
      } else {
        outF[(size_t)row * HID + n0 + cc] = v0;
        outF[(size_t)row * HID + n0 + 16 + cc] = v1;
      }
    }
  }
}

// ---------------------------------------------------------------------------
// K6: final layer, 4 outputs per point, shuffle reduce; un-permutes sorted
// order on the output scatter (byte-identical to R9).
// ---------------------------------------------------------------------------
__global__ __launch_bounds__(256) void k_out(const float* __restrict__ h,
                                             const float* __restrict__ W3,
                                             const float* __restrict__ b3,
                                             const int* __restrict__ perm,
                                             float* __restrict__ out) {
  int gp = blockIdx.x * 4 + (threadIdx.x >> 6);
  int lane = threadIdx.x & 63;
  const float* hr = h + (size_t)gp * HID;
  float4 hv = *(const float4*)&hr[lane * 4];
  float s[4];
#pragma unroll
  for (int o = 0; o < 4; ++o) {
    float4 w = *(const float4*)&W3[o * HID + lane * 4];
    s[o] = hv.x * w.x + hv.y * w.y + hv.z * w.z + hv.w * w.w;
  }
#pragma unroll
  for (int off = 32; off; off >>= 1)
#pragma unroll
    for (int o = 0; o < 4; ++o) s[o] += __shfl_xor(s[o], off, 64);
  if (lane == 0) {
    int b = gp / NP, ns = gp % NP;
    int n = perm[(size_t)b * NP + ns];
#pragma unroll
    for (int o = 0; o < 4; ++o)
      out[((size_t)b * OUTC + o) * NP + n] = s[o] + b3[o];
  }
}

extern "C" void kernel_launch(void* const* d_in, const int* in_sizes, int n_in,
                              void* d_out, int out_size, void* d_ws, size_t ws_size,
                              hipStream_t stream) {
  const float* fine = (const float*)d_in[0];
  const float* coarse = (const float*)d_in[1];
  const float* logits = (const float*)d_in[2];
  const float* rand_points = (const float*)d_in[3];
  const float* rand_extra = (const float*)d_in[4];
  const float* W1 = (const float*)d_in[5];
  const float* b1 = (const float*)d_in[6];
  const float* W2 = (const float*)d_in[7];
  const float* b2 = (const float*)d_in[8];
  const float* W3 = (const float*)d_in[9];
  const float* b3 = (const float*)d_in[10];
  float* out = (float*)d_out;

  float* out_logits = out;
  float* out_points = out + (size_t)BATCH * OUTC * NP;

  // ws layout (bytes)
  char* ws = (char*)d_ws;
  float* u = (float*)(ws + 0);                         // 196608
  int2* m2 = (int2*)(ws + 196608);                     // 131072
  float4* wts = (float4*)(ws + 327680);                // 262144
  int2* m2s = (int2*)(ws + 589824);                    // 131072
  float4* wtss = (float4*)(ws + 720896);               // 262144
  int* perm = (int*)(ws + 983040);                     // 65536
  float* featsT = (float*)(ws + 1048576);              // 12582912
  unsigned short* AH = (unsigned short*)(ws + 13631488);   // 6291456
  unsigned short* AL = (unsigned short*)(ws + 19922944);   // 6291456
  unsigned short* W1H = (unsigned short*)(ws + 26214400);  // 98304
  unsigned short* W1L = (unsigned short*)(ws + 26312704);  // 98304
  unsigned short* W2H = (unsigned short*)(ws + 26411008);  // 131072
  unsigned short* W2L = (unsigned short*)(ws + 26542080);  // 131072
  unsigned short* h1H = (unsigned short*)(ws + 26673152);  // 8388608
  unsigned short* h1L = (unsigned short*)(ws + 35061760);  // 8388608
  float* h2 = (float*)(ws + 43450368);                     // 16777216

  k_uncert<<<(BATCH * NS + 255) / 256, 256, 0, stream>>>(logits, rand_points, u);
  k_convW<<<(HID * CIN + 255) / 256, 256, 0, stream>>>(W1, W1H, W1L, HID * CIN);
  k_convW<<<(HID * HID + 255) / 256, 256, 0, stream>>>(W2, W2H, W2L, HID * HID);
  k_select<<<BATCH * (NS / 256), 256, 0, stream>>>(u, rand_points, out_points);
  k_extra<<<(BATCH * NR + 255) / 256, 256, 0, stream>>>(rand_extra, out_points);
  k_prep<<<(M_TOT + 255) / 256, 256, 0, stream>>>(out_points, m2, wts);
  k_sort<<<BATCH, 512, 0, stream>>>(m2, perm);
  k_reorder<<<(M_TOT + 255) / 256, 256, 0, stream>>>(perm, m2, wts, m2s, wtss);
  k_gather5<<<CIN * BATCH * GCH_SPLIT, 256, 0, stream>>>(fine, coarse, m2s,
                                                         wtss, featsT);
  k_convA<<<(CIN / 32) * (M_TOT / 64), 256, 0, stream>>>(featsT, AH, AL);
  k_mfma<CIN, true><<<dim3(HID / 64, M_TOT / 64), 256, 0, stream>>>(
      AH, AL, W1H, W1L, b1, nullptr, h1H, h1L);
  k_mfma<HID, false><<<dim3(HID / 64, M_TOT / 64), 256, 0, stream>>>(
      h1H, h1L, W2H, W2L, b2, h2, nullptr, nullptr);
  k_out<<<M_TOT / 4, 256, 0, stream>>>(h2, W3, b3, perm, out_logits);
}

// Round 11
// 310.537 us; speedup vs baseline: 1.0158x; 1.0158x over previous
//
#include <hip/hip_runtime.h>
#include <math.h>

// Problem constants (from reference)
#define BATCH 4
#define HW 512
#define NPLANE (512 * 512)
#define NS 12288      // oversampled points per batch
#define NU 3072       // top-k uncertain selected
#define NR 1024       // random extra points
#define NP 4096       // total selected points per batch
#define CF_CH 64
#define CC_CH 128
#define CIN 192
#define HID 256
#define OUTC 4
#define M_TOT (BATCH * NP)  // 16384
#define GCH_SPLIT 4         // point-chunks per (batch, channel) in gather

// ---------------------------------------------------------------------------
// Bit-exact replication of XLA:CPU's vectorized f32 expf (Cephes polynomial),
// strict per-op f32 rounding, no FMA. DO NOT TOUCH — top-k order depends on it.
// ---------------------------------------------------------------------------
__device__ __forceinline__ float xla_expf(float xin) {
  float x = fminf(fmaxf(xin, -88.3762626647949f), 88.3762626647950f);
  float fx = floorf(__fadd_rn(__fmul_rn(x, 1.44269504088896341f), 0.5f));
  float tmp = __fmul_rn(0.693359375f, fx);
  float z = __fmul_rn(-2.12194440e-4f, fx);
  x = __fsub_rn(__fsub_rn(x, tmp), z);
  float y = __fadd_rn(__fmul_rn(x, 1.9875691500E-4f), 1.3981999507E-3f);
  y = __fadd_rn(__fmul_rn(y, x), 8.3334519073E-3f);
  y = __fadd_rn(__fmul_rn(y, x), 4.1665795894E-2f);
  y = __fadd_rn(__fmul_rn(y, x), 1.6666665459E-1f);
  y = __fadd_rn(__fmul_rn(y, x), 5.0000001201E-1f);
  z = __fmul_rn(x, x);
  y = __fadd_rn(__fmul_rn(y, z), x);
  y = __fadd_rn(y, 1.0f);
  int n = (int)fx;
  float p2n = __int_as_float((n + 127) << 23);
  return __fmul_rn(y, p2n);
}

// ---------------------------------------------------------------------------
// K1: uncertainty at oversampled points fused with random-extra append
// (disjoint thread ranges; both halves R7-verified numerically).
// ---------------------------------------------------------------------------
__global__ void k_uncert_extra(const float* __restrict__ logits,
                               const float* __restrict__ rp,
                               const float* __restrict__ re,
                               float* __restrict__ u,
                               float* __restrict__ pts_out) {
  int gid = blockIdx.x * 256 + threadIdx.x;
  if (gid < BATCH * NS) {
    int b = gid / NS;
    float px = rp[(size_t)gid * 2 + 0];
    float py = rp[(size_t)gid * 2 + 1];
    const float* plane = logits + (size_t)b * OUTC * NPLANE;  // channel 0

    float x = __fsub_rn(__fmul_rn(px, 512.0f), 0.5f);
    float y = __fsub_rn(__fmul_rn(py, 512.0f), 0.5f);
    float x0f = floorf(x), y0f = floorf(y);
    float wx = __fsub_rn(x, x0f);
    float wy = __fsub_rn(y, y0f);
    int x0 = (int)x0f, y0 = (int)y0f;
    int x1 = x0 + 1, y1 = y0 + 1;
    bool vx0 = (x0 >= 0) & (x0 < HW);
    bool vx1 = (x1 >= 0) & (x1 < HW);
    bool vy0 = (y0 >= 0) & (y0 < HW);
    bool vy1 = (y1 >= 0) & (y1 < HW);
    float g00 = (vx0 && vy0) ? plane[y0 * HW + x0] : 0.0f;
    float g10 = (vx1 && vy0) ? plane[y0 * HW + x1] : 0.0f;
    float g01 = (vx0 && vy1) ? plane[y1 * HW + x0] : 0.0f;
    float g11 = (vx1 && vy1) ? plane[y1 * HW + x1] : 0.0f;
    float omx = __fsub_rn(1.0f, wx);
    float omy = __fsub_rn(1.0f, wy);
    float w00 = __fmul_rn(omx, omy);
    float w10 = __fmul_rn(wx, omy);
    float w01 = __fmul_rn(omx, wy);
    float w11 = __fmul_rn(wx, wy);
    float s = __fadd_rn(
        __fadd_rn(__fadd_rn(__fmul_rn(g00, w00), __fmul_rn(g10, w10)),
                  __fmul_rn(g01, w01)),
        __fmul_rn(g11, w11));
    float e = xla_expf(-s);
    float sig = __fdiv_rn(1.0f, __fadd_rn(1.0f, e));
    float t = __fmul_rn(fabsf(__fsub_rn(sig, 0.5f)), 2.0f);
    u[gid] = __fsub_rn(1.0f, t);
  } else {
    int g = gid - BATCH * NS;  // [0, BATCH*NR)
    if (g < BATCH * NR) {
      int b = g / NR, j = g - b * NR;
      pts_out[((size_t)b * NP + NU + j) * 2 + 0] = re[(size_t)g * 2 + 0];
      pts_out[((size_t)b * NP + NU + j) * 2 + 1] = re[(size_t)g * 2 + 1];
    }
  }
}

// ---------------------------------------------------------------------------
// K2: exact stable top-k via ranking (R6-verified, byte-identical). CLOSED.
// ---------------------------------------------------------------------------
__global__ __launch_bounds__(256) void k_select(const float* __restrict__ u,
                                                const float* __restrict__ rp,
                                                float* __restrict__ pts_out) {
  __shared__ __align__(16) float su[NS];
  int b = blockIdx.x / (NS / 256);
  int blk = blockIdx.x % (NS / 256);
  const float* ub = u + (size_t)b * NS;
  for (int t = threadIdx.x; t < NS / 4; t += 256)
    ((float4*)su)[t] = ((const float4*)ub)[t];
  __syncthreads();
  int i = blk * 256 + (int)threadIdx.x;
  int wb = i & ~63;  // wave-uniform (blk*256 is 64-aligned)
  float ui = su[i];
  int r0 = 0, r1 = 0, r2 = 0, r3 = 0;
  for (int j = 0; j < wb; j += 8) {
    float4 v = *(const float4*)&su[j];
    float4 w = *(const float4*)&su[j + 4];
    r0 += (v.x >= ui) + (w.x >= ui);
    r1 += (v.y >= ui) + (w.y >= ui);
    r2 += (v.z >= ui) + (w.z >= ui);
    r3 += (v.w >= ui) + (w.w >= ui);
  }
  for (int j = wb; j < wb + 64; ++j) {
    float vj = su[j];
    r0 += (vj > ui) || (vj == ui && j < i);
  }
  for (int j = wb + 64; j < NS; j += 8) {
    float4 v = *(const float4*)&su[j];
    float4 w = *(const float4*)&su[j + 4];
    r0 += (v.x > ui) + (w.x > ui);
    r1 += (v.y > ui) + (w.y > ui);
    r2 += (v.z > ui) + (w.z > ui);
    r3 += (v.w > ui) + (w.w > ui);
  }
  int rank = (r0 + r1) + (r2 + r3);
  if (rank < NU) {
    pts_out[((size_t)b * NP + rank) * 2 + 0] = rp[((size_t)b * NS + i) * 2 + 0];
    pts_out[((size_t)b * NP + rank) * 2 + 1] = rp[((size_t)b * NS + i) * 2 + 1];
  }
}

// ---------------------------------------------------------------------------
// K3a: per-point bilinear metadata (byte-identical, R9-verified).
// ---------------------------------------------------------------------------
__global__ void k_prep(const float* __restrict__ pts, int2* __restrict__ m2,
                       float4* __restrict__ wts) {
  int g = blockIdx.x * 256 + threadIdx.x;
  if (g >= M_TOT) return;
  float px = pts[(size_t)g * 2 + 0];
  float py = pts[(size_t)g * 2 + 1];
  float x = px * 512.0f - 0.5f;
  float y = py * 512.0f - 0.5f;
  float x0f = floorf(x), y0f = floorf(y);
  float wx = x - x0f, wy = y - y0f;
  int x0 = (int)x0f, y0 = (int)y0f;
  bool vx0 = (unsigned)x0 < (unsigned)HW;
  bool vx1 = (unsigned)(x0 + 1) < (unsigned)HW;
  bool vy0 = (unsigned)y0 < (unsigned)HW;
  bool vy1 = (unsigned)(y0 + 1) < (unsigned)HW;
  int vm = (int)(vx0 && vy0) | ((int)(vx1 && vy0) << 1) |
           ((int)(vx0 && vy1) << 2) | ((int)(vx1 && vy1) << 3);
  m2[g] = make_int2(y0 * HW + x0, vm);
  wts[g] = make_float4((1.0f - wx) * (1.0f - wy), wx * (1.0f - wy),
                       (1.0f - wx) * wy, wx * wy);
}

// ---------------------------------------------------------------------------
// K3b: counting-sort by row (byte-identical, R9-verified).
// ---------------------------------------------------------------------------
__global__ __launch_bounds__(512) void k_sort(const int2* __restrict__ m2,
                                              int* __restrict__ perm) {
  __shared__ int hist[512], pref[512];
  int b = blockIdx.x, tid = threadIdx.x;
  hist[tid] = 0;
  __syncthreads();
  for (int p = tid; p < NP; p += 512) {
    int i00 = m2[(size_t)b * NP + p].x;
    int key = min(max(i00, 0), NPLANE - 1) >> 9;
    atomicAdd(&hist[key], 1);
  }
  __syncthreads();
  int v = hist[tid];
  pref[tid] = v;
  __syncthreads();
  for (int d = 1; d < 512; d <<= 1) {
    int t = (tid >= d) ? pref[tid - d] : 0;
    __syncthreads();
    pref[tid] += t;
    __syncthreads();
  }
  hist[tid] = pref[tid] - v;
  __syncthreads();
  for (int p = tid; p < NP; p += 512) {
    int i00 = m2[(size_t)b * NP + p].x;
    int key = min(max(i00, 0), NPLANE - 1) >> 9;
    int pos = atomicAdd(&hist[key], 1);
    perm[(size_t)b * NP + pos] = p;
  }
}

// ---------------------------------------------------------------------------
// K3c: materialize metadata in sorted order (byte-identical, R9-verified).
// ---------------------------------------------------------------------------
__global__ void k_reorder(const int* __restrict__ perm,
                          const int2* __restrict__ m2,
                          const float4* __restrict__ wts,
                          int2* __restrict__ m2s, float4* __restrict__ wtss) {
  int gid = blockIdx.x * 256 + threadIdx.x;
  if (gid >= M_TOT) return;
  int b = gid / NP;
  int p = perm[gid];
  m2s[gid] = m2[(size_t)b * NP + p];
  wtss[gid] = wts[(size_t)b * NP + p];
}

// ---------------------------------------------------------------------------
// K3d: gather in sorted point order (byte-identical, R9-verified).
// featsT[c][b*NP + s] with s in sorted space.
// ---------------------------------------------------------------------------
__global__ __launch_bounds__(256) void k_gather5(
    const float* __restrict__ fine, const float* __restrict__ coarse,
    const int2* __restrict__ m2s, const float4* __restrict__ wtss,
    float* __restrict__ featsT) {
  int c = blockIdx.x % CIN;
  int rem = blockIdx.x / CIN;
  int b = rem & (BATCH - 1);
  int part = rem >> 2;
  const float* plane = (c < CF_CH)
                           ? fine + ((size_t)b * CF_CH + c) * NPLANE
                           : coarse + ((size_t)b * CC_CH + (c - CF_CH)) * NPLANE;
  const int2* m2b = m2s + (size_t)b * NP;
  const float4* wtsb = wtss + (size_t)b * NP;
  float* outrow = featsT + (size_t)c * M_TOT + (size_t)b * NP;
  int s0 = part * (NP / GCH_SPLIT);
#pragma unroll
  for (int q = 0; q < NP / GCH_SPLIT / 256; ++q) {
    int s = s0 + q * 256 + (int)threadIdx.x;
    int2 mm = m2b[s];
    float4 w = wtsb[s];
    const float* bp = plane + mm.x;
    float t00 = 0.0f, t10 = 0.0f, t01 = 0.0f, t11 = 0.0f;
    if (mm.y & 1) t00 = bp[0] * w.x;
    if (mm.y & 2) t10 = bp[1] * w.y;
    if (mm.y & 4) t01 = bp[HW] * w.z;
    if (mm.y & 8) t11 = bp[HW + 1] * w.w;
    outrow[s] = ((t00 + t10) + t01) + t11;
  }
}

// ---------------------------------------------------------------------------
// K4: GEMM layer 1 from transposed A (At[k][m]), C[M][256] row-major.
// 64x64 tile, BK=32, 256 threads, 4x4 acc. (R9-verified, byte-identical.)
// ---------------------------------------------------------------------------
__global__ __launch_bounds__(256) void k_gemm1_At(const float* __restrict__ At,
                                                  const float* __restrict__ W,
                                                  const float* __restrict__ bias,
                                                  float* __restrict__ C) {
  __shared__ __align__(16) float As[32][68];
  __shared__ __align__(16) float Bs[32][68];
  const int bx = blockIdx.x & 3;   // N tile
  const int by = blockIdx.x >> 2;  // M tile
  const int tid = threadIdx.x;
  const int tn = tid & 15, tm = tid >> 4;
  const int m_base = by * 64, n_base = bx * 64;
  float acc[4][4] = {};
  for (int k0 = 0; k0 < CIN; k0 += 32) {
#pragma unroll
    for (int r = 0; r < 2; ++r) {
      int t = tid + r * 256;
      int kk = t >> 4, mg = (t & 15) * 4;
      *(float4*)&As[kk][mg] =
          *(const float4*)&At[(size_t)(k0 + kk) * M_TOT + m_base + mg];
      int row = t >> 3, cg = (t & 7) * 4;
      float4 vw = *(const float4*)&W[(size_t)(n_base + row) * CIN + k0 + cg];
      Bs[cg + 0][row] = vw.x;
      Bs[cg + 1][row] = vw.y;
      Bs[cg + 2][row] = vw.z;
      Bs[cg + 3][row] = vw.w;
    }
    __syncthreads();
#pragma unroll
    for (int kk = 0; kk < 32; ++kk) {
      float4 a4 = *(const float4*)&As[kk][tm * 4];
      float4 b4 = *(const float4*)&Bs[kk][tn * 4];
      float av[4] = {a4.x, a4.y, a4.z, a4.w};
      float bw[4] = {b4.x, b4.y, b4.z, b4.w};
#pragma unroll
      for (int i = 0; i < 4; ++i)
#pragma unroll
        for (int j = 0; j < 4; ++j) acc[i][j] = fmaf(av[i], bw[j], acc[i][j]);
    }
    __syncthreads();
  }
  float bs[4];
#pragma unroll
  for (int j = 0; j < 4; ++j) bs[j] = bias[n_base + tn * 4 + j];
#pragma unroll
  for (int i = 0; i < 4; ++i) {
    float4 o;
    o.x = fmaxf(acc[i][0] + bs[0], 0.0f);
    o.y = fmaxf(acc[i][1] + bs[1], 0.0f);
    o.z = fmaxf(acc[i][2] + bs[2], 0.0f);
    o.w = fmaxf(acc[i][3] + bs[3], 0.0f);
    *(float4*)&C[(size_t)(m_base + tm * 4 + i) * HID + n_base + tn * 4] = o;
  }
}

// ---------------------------------------------------------------------------
// K5: GEMM layer 2 fused with layer 3 and the un-permuting output scatter.
// One block per 64 points computes the FULL 64x256 h2 tile (W2 k-slab staged
// in LDS), applies bias+relu in registers, dots with W3 per-thread (16 cols),
// shfl-reduces across the 16 tn-lanes, and writes the 4 logits directly.
// Eliminates the h2 buffer (32 MB traffic) and the k_out kernel.
// Thread map: tm=tid>>4 -> rows tm*4..+3; tn=tid&15 -> cols tn*16..+15.
// ---------------------------------------------------------------------------
__global__ __launch_bounds__(256) void k_gemm2_fused(
    const float* __restrict__ A,     // h1 [M][256]
    const float* __restrict__ W,     // W2 [256][256]
    const float* __restrict__ bias,  // b2
    const float* __restrict__ W3,    // [4][256]
    const float* __restrict__ b3,
    const int* __restrict__ perm,
    float* __restrict__ out) {       // [B][4][NP]
  __shared__ __align__(16) float As[32][68];
  __shared__ __align__(16) float Bs[32][260];
  const int tid = threadIdx.x;
  const int tm = tid >> 4, tn = tid & 15;
  const int m_base = blockIdx.x * 64;
  float acc[4][16] = {};
  for (int k0 = 0; k0 < HID; k0 += 32) {
#pragma unroll
    for (int r = 0; r < 2; ++r) {  // A tile 64x32
      int t = tid + r * 256;
      int row = t >> 3, cg = (t & 7) * 4;
      float4 va = *(const float4*)&A[(size_t)(m_base + row) * HID + k0 + cg];
      As[cg + 0][row] = va.x;
      As[cg + 1][row] = va.y;
      As[cg + 2][row] = va.z;
      As[cg + 3][row] = va.w;
    }
#pragma unroll
    for (int r = 0; r < 8; ++r) {  // W2 slab 256x32 -> Bs[kk][n]
      int t = tid + r * 256;
      int row = t >> 3, cg = (t & 7) * 4;
      float4 vw = *(const float4*)&W[(size_t)row * HID + k0 + cg];
      Bs[cg + 0][row] = vw.x;
      Bs[cg + 1][row] = vw.y;
      Bs[cg + 2][row] = vw.z;
      Bs[cg + 3][row] = vw.w;
    }
    __syncthreads();
#pragma unroll
    for (int kk = 0; kk < 32; ++kk) {
      float a4[4];
      *(float4*)a4 = *(const float4*)&As[kk][tm * 4];
      float bw[16];
#pragma unroll
      for (int j = 0; j < 4; ++j)
        *(float4*)&bw[j * 4] = *(const float4*)&Bs[kk][tn * 16 + j * 4];
#pragma unroll
      for (int i = 0; i < 4; ++i)
#pragma unroll
        for (int j = 0; j < 16; ++j)
          acc[i][j] = fmaf(a4[i], bw[j], acc[i][j]);
    }
    __syncthreads();
  }
  // bias + relu + fused layer-3 partials over this thread's 16 columns
  float p[4][4] = {};  // [row i][output o]
#pragma unroll
  for (int j = 0; j < 16; ++j) {
    int n = tn * 16 + j;
    float bn = bias[n];
    float w3v[4];
#pragma unroll
    for (int o = 0; o < 4; ++o) w3v[o] = W3[o * HID + n];
#pragma unroll
    for (int i = 0; i < 4; ++i) {
      float h = fmaxf(acc[i][j] + bn, 0.0f);
#pragma unroll
      for (int o = 0; o < 4; ++o) p[i][o] = fmaf(h, w3v[o], p[i][o]);
    }
  }
  // reduce across the 16 tn-lanes (consecutive lanes, offsets < 16)
#pragma unroll
  for (int off = 8; off; off >>= 1)
#pragma unroll
    for (int i = 0; i < 4; ++i)
#pragma unroll
      for (int o = 0; o < 4; ++o) p[i][o] += __shfl_xor(p[i][o], off, 64);
  if (tn == 0) {
    int b = (int)blockIdx.x / (NP / 64);
#pragma unroll
    for (int i = 0; i < 4; ++i) {
      int ms = m_base + tm * 4 + i;                     // sorted global index
      int n = perm[(size_t)b * NP + (ms - b * NP)];     // original index
#pragma unroll
      for (int o = 0; o < 4; ++o)
        out[((size_t)b * OUTC + o) * NP + n] = p[i][o] + b3[o];
    }
  }
}

extern "C" void kernel_launch(void* const* d_in, const int* in_sizes, int n_in,
                              void* d_out, int out_size, void* d_ws, size_t ws_size,
                              hipStream_t stream) {
  const float* fine = (const float*)d_in[0];
  const float* coarse = (const float*)d_in[1];
  const float* logits = (const float*)d_in[2];
  const float* rand_points = (const float*)d_in[3];
  const float* rand_extra = (const float*)d_in[4];
  const float* W1 = (const float*)d_in[5];
  const float* b1 = (const float*)d_in[6];
  const float* W2 = (const float*)d_in[7];
  const float* b2 = (const float*)d_in[8];
  const float* W3 = (const float*)d_in[9];
  const float* b3 = (const float*)d_in[10];
  float* out = (float*)d_out;

  float* out_logits = out;
  float* out_points = out + (size_t)BATCH * OUTC * NP;

  // ws layout (bytes): u | m2 | wts | m2s | wtss | perm | featsT | h1
  char* ws = (char*)d_ws;
  float* u = (float*)(ws + 0);               // 196608
  int2* m2 = (int2*)(ws + 196608);           // 131072
  float4* wts = (float4*)(ws + 327680);      // 262144
  int2* m2s = (int2*)(ws + 589824);          // 131072
  float4* wtss = (float4*)(ws + 720896);     // 262144
  int* perm = (int*)(ws + 983040);           // 65536
  float* featsT = (float*)(ws + 1048576);    // 12582912
  float* h1 = (float*)(ws + 13631488);       // 16777216

  k_uncert_extra<<<(BATCH * NS + BATCH * NR + 255) / 256, 256, 0, stream>>>(
      logits, rand_points, rand_extra, u, out_points);
  k_select<<<BATCH * (NS / 256), 256, 0, stream>>>(u, rand_points, out_points);
  k_prep<<<(M_TOT + 255) / 256, 256, 0, stream>>>(out_points, m2, wts);
  k_sort<<<BATCH, 512, 0, stream>>>(m2, perm);
  k_reorder<<<(M_TOT + 255) / 256, 256, 0, stream>>>(perm, m2, wts, m2s, wtss);
  k_gather5<<<CIN * BATCH * GCH_SPLIT, 256, 0, stream>>>(fine, coarse, m2s,
                                                         wtss, featsT);
  k_gemm1_At<<<(M_TOT / 64) * 4, 256, 0, stream>>>(featsT, W1, b1, h1);
  k_gemm2_fused<<<M_TOT / 64, 256, 0, stream>>>(h1, W2, b2, W3, b3, perm,
                                                out_logits);
}

// Round 12
// 300.750 us; speedup vs baseline: 1.0489x; 1.0325x over previous
//
#include <hip/hip_runtime.h>
#include <math.h>

// Problem constants (from reference)
#define BATCH 4
#define HW 512
#define NPLANE (512 * 512)
#define NS 12288      // oversampled points per batch
#define NU 3072       // top-k uncertain selected
#define NR 1024       // random extra points
#define NP 4096       // total selected points per batch
#define CF_CH 64
#define CC_CH 128
#define CIN 192
#define HID 256
#define OUTC 4
#define M_TOT (BATCH * NP)  // 16384
#define GCH_SPLIT 8         // point-chunks per (batch, channel) in gather

// ---------------------------------------------------------------------------
// Bit-exact replication of XLA:CPU's vectorized f32 expf (Cephes polynomial),
// strict per-op f32 rounding, no FMA. DO NOT TOUCH — top-k order depends on it.
// ---------------------------------------------------------------------------
__device__ __forceinline__ float xla_expf(float xin) {
  float x = fminf(fmaxf(xin, -88.3762626647949f), 88.3762626647950f);
  float fx = floorf(__fadd_rn(__fmul_rn(x, 1.44269504088896341f), 0.5f));
  float tmp = __fmul_rn(0.693359375f, fx);
  float z = __fmul_rn(-2.12194440e-4f, fx);
  x = __fsub_rn(__fsub_rn(x, tmp), z);
  float y = __fadd_rn(__fmul_rn(x, 1.9875691500E-4f), 1.3981999507E-3f);
  y = __fadd_rn(__fmul_rn(y, x), 8.3334519073E-3f);
  y = __fadd_rn(__fmul_rn(y, x), 4.1665795894E-2f);
  y = __fadd_rn(__fmul_rn(y, x), 1.6666665459E-1f);
  y = __fadd_rn(__fmul_rn(y, x), 5.0000001201E-1f);
  z = __fmul_rn(x, x);
  y = __fadd_rn(__fmul_rn(y, z), x);
  y = __fadd_rn(y, 1.0f);
  int n = (int)fx;
  float p2n = __int_as_float((n + 127) << 23);
  return __fmul_rn(y, p2n);
}

// ---------------------------------------------------------------------------
// K1: uncertainty at oversampled points fused with random-extra append
// (R7/R11-verified, byte-identical).
// ---------------------------------------------------------------------------
__global__ void k_uncert_extra(const float* __restrict__ logits,
                               const float* __restrict__ rp,
                               const float* __restrict__ re,
                               float* __restrict__ u,
                               float* __restrict__ pts_out) {
  int gid = blockIdx.x * 256 + threadIdx.x;
  if (gid < BATCH * NS) {
    int b = gid / NS;
    float px = rp[(size_t)gid * 2 + 0];
    float py = rp[(size_t)gid * 2 + 1];
    const float* plane = logits + (size_t)b * OUTC * NPLANE;  // channel 0

    float x = __fsub_rn(__fmul_rn(px, 512.0f), 0.5f);
    float y = __fsub_rn(__fmul_rn(py, 512.0f), 0.5f);
    float x0f = floorf(x), y0f = floorf(y);
    float wx = __fsub_rn(x, x0f);
    float wy = __fsub_rn(y, y0f);
    int x0 = (int)x0f, y0 = (int)y0f;
    int x1 = x0 + 1, y1 = y0 + 1;
    bool vx0 = (x0 >= 0) & (x0 < HW);
    bool vx1 = (x1 >= 0) & (x1 < HW);
    bool vy0 = (y0 >= 0) & (y0 < HW);
    bool vy1 = (y1 >= 0) & (y1 < HW);
    float g00 = (vx0 && vy0) ? plane[y0 * HW + x0] : 0.0f;
    float g10 = (vx1 && vy0) ? plane[y0 * HW + x1] : 0.0f;
    float g01 = (vx0 && vy1) ? plane[y1 * HW + x0] : 0.0f;
    float g11 = (vx1 && vy1) ? plane[y1 * HW + x1] : 0.0f;
    float omx = __fsub_rn(1.0f, wx);
    float omy = __fsub_rn(1.0f, wy);
    float w00 = __fmul_rn(omx, omy);
    float w10 = __fmul_rn(wx, omy);
    float w01 = __fmul_rn(omx, wy);
    float w11 = __fmul_rn(wx, wy);
    float s = __fadd_rn(
        __fadd_rn(__fadd_rn(__fmul_rn(g00, w00), __fmul_rn(g10, w10)),
                  __fmul_rn(g01, w01)),
        __fmul_rn(g11, w11));
    float e = xla_expf(-s);
    float sig = __fdiv_rn(1.0f, __fadd_rn(1.0f, e));
    float t = __fmul_rn(fabsf(__fsub_rn(sig, 0.5f)), 2.0f);
    u[gid] = __fsub_rn(1.0f, t);
  } else {
    int g = gid - BATCH * NS;  // [0, BATCH*NR)
    if (g < BATCH * NR) {
      int b = g / NR, j = g - b * NR;
      pts_out[((size_t)b * NP + NU + j) * 2 + 0] = re[(size_t)g * 2 + 0];
      pts_out[((size_t)b * NP + NU + j) * 2 + 1] = re[(size_t)g * 2 + 1];
    }
  }
}

// ---------------------------------------------------------------------------
// K2: exact stable top-k via ranking (R6-verified, byte-identical). CLOSED.
// ---------------------------------------------------------------------------
__global__ __launch_bounds__(256) void k_select(const float* __restrict__ u,
                                                const float* __restrict__ rp,
                                                float* __restrict__ pts_out) {
  __shared__ __align__(16) float su[NS];
  int b = blockIdx.x / (NS / 256);
  int blk = blockIdx.x % (NS / 256);
  const float* ub = u + (size_t)b * NS;
  for (int t = threadIdx.x; t < NS / 4; t += 256)
    ((float4*)su)[t] = ((const float4*)ub)[t];
  __syncthreads();
  int i = blk * 256 + (int)threadIdx.x;
  int wb = i & ~63;  // wave-uniform (blk*256 is 64-aligned)
  float ui = su[i];
  int r0 = 0, r1 = 0, r2 = 0, r3 = 0;
  for (int j = 0; j < wb; j += 8) {
    float4 v = *(const float4*)&su[j];
    float4 w = *(const float4*)&su[j + 4];
    r0 += (v.x >= ui) + (w.x >= ui);
    r1 += (v.y >= ui) + (w.y >= ui);
    r2 += (v.z >= ui) + (w.z >= ui);
    r3 += (v.w >= ui) + (w.w >= ui);
  }
  for (int j = wb; j < wb + 64; ++j) {
    float vj = su[j];
    r0 += (vj > ui) || (vj == ui && j < i);
  }
  for (int j = wb + 64; j < NS; j += 8) {
    float4 v = *(const float4*)&su[j];
    float4 w = *(const float4*)&su[j + 4];
    r0 += (v.x > ui) + (w.x > ui);
    r1 += (v.y > ui) + (w.y > ui);
    r2 += (v.z > ui) + (w.z > ui);
    r3 += (v.w > ui) + (w.w > ui);
  }
  int rank = (r0 + r1) + (r2 + r3);
  if (rank < NU) {
    pts_out[((size_t)b * NP + rank) * 2 + 0] = rp[((size_t)b * NS + i) * 2 + 0];
    pts_out[((size_t)b * NP + rank) * 2 + 1] = rp[((size_t)b * NS + i) * 2 + 1];
  }
}

// ---------------------------------------------------------------------------
// K3: fused metadata + row-sort + sorted materialization (replaces R9's
// k_prep + k_sort + k_reorder). One block per batch, 512 threads. Metadata FP
// expressions identical to R9's k_prep (bit-identical values); histogram/scan
// identical to R9's k_sort; wts recomputed from registers at scatter time.
// Within-bucket order nondeterministic but un-applied at k_out (R9-proven).
// ---------------------------------------------------------------------------
__global__ __launch_bounds__(512) void k_meta(const float* __restrict__ pts,
                                              int2* __restrict__ m2s,
                                              float4* __restrict__ wtss,
                                              int* __restrict__ perm) {
  __shared__ int2 marr[NP];  // 32 KB
  __shared__ int hist[512], pref[512];
  int b = blockIdx.x, tid = threadIdx.x;
  hist[tid] = 0;
  __syncthreads();
  float pxr[8], pyr[8];
#pragma unroll
  for (int q = 0; q < 8; ++q) {
    int p = q * 512 + tid;
    float px = pts[((size_t)b * NP + p) * 2 + 0];
    float py = pts[((size_t)b * NP + p) * 2 + 1];
    pxr[q] = px;
    pyr[q] = py;
    float x = px * 512.0f - 0.5f;
    float y = py * 512.0f - 0.5f;
    float x0f = floorf(x), y0f = floorf(y);
    int x0 = (int)x0f, y0 = (int)y0f;
    bool vx0 = (unsigned)x0 < (unsigned)HW;
    bool vx1 = (unsigned)(x0 + 1) < (unsigned)HW;
    bool vy0 = (unsigned)y0 < (unsigned)HW;
    bool vy1 = (unsigned)(y0 + 1) < (unsigned)HW;
    int vm = (int)(vx0 && vy0) | ((int)(vx1 && vy0) << 1) |
             ((int)(vx0 && vy1) << 2) | ((int)(vx1 && vy1) << 3);
    int i00 = y0 * HW + x0;
    marr[p] = make_int2(i00, vm);
    int key = min(max(i00, 0), NPLANE - 1) >> 9;
    atomicAdd(&hist[key], 1);
  }
  __syncthreads();
  int v = hist[tid];
  pref[tid] = v;
  __syncthreads();
  for (int d = 1; d < 512; d <<= 1) {
    int t = (tid >= d) ? pref[tid - d] : 0;
    __syncthreads();
    pref[tid] += t;
    __syncthreads();
  }
  hist[tid] = pref[tid] - v;  // exclusive prefix -> running offsets
  __syncthreads();
#pragma unroll
  for (int q = 0; q < 8; ++q) {
    int p = q * 512 + tid;
    int2 mm = marr[p];
    int key = min(max(mm.x, 0), NPLANE - 1) >> 9;
    int pos = atomicAdd(&hist[key], 1);
    perm[(size_t)b * NP + pos] = p;
    m2s[(size_t)b * NP + pos] = mm;
    float x = pxr[q] * 512.0f - 0.5f;
    float y = pyr[q] * 512.0f - 0.5f;
    float wx = x - floorf(x), wy = y - floorf(y);
    wtss[(size_t)b * NP + pos] =
        make_float4((1.0f - wx) * (1.0f - wy), wx * (1.0f - wy),
                    (1.0f - wx) * wy, wx * wy);
  }
}

// ---------------------------------------------------------------------------
// K4: gather in sorted point order (R9-verified body; GCH_SPLIT=8 -> 6144
// blocks for better CU load balance). featsT[c][b*NP + s], s in sorted space.
// ---------------------------------------------------------------------------
__global__ __launch_bounds__(256) void k_gather5(
    const float* __restrict__ fine, const float* __restrict__ coarse,
    const int2* __restrict__ m2s, const float4* __restrict__ wtss,
    float* __restrict__ featsT) {
  int c = blockIdx.x % CIN;
  int rem = blockIdx.x / CIN;
  int b = rem & (BATCH - 1);
  int part = rem >> 2;
  const float* plane = (c < CF_CH)
                           ? fine + ((size_t)b * CF_CH + c) * NPLANE
                           : coarse + ((size_t)b * CC_CH + (c - CF_CH)) * NPLANE;
  const int2* m2b = m2s + (size_t)b * NP;
  const float4* wtsb = wtss + (size_t)b * NP;
  float* outrow = featsT + (size_t)c * M_TOT + (size_t)b * NP;
  int s0 = part * (NP / GCH_SPLIT);
#pragma unroll
  for (int q = 0; q < NP / GCH_SPLIT / 256; ++q) {
    int s = s0 + q * 256 + (int)threadIdx.x;
    int2 mm = m2b[s];
    float4 w = wtsb[s];
    const float* bp = plane + mm.x;
    float t00 = 0.0f, t10 = 0.0f, t01 = 0.0f, t11 = 0.0f;
    if (mm.y & 1) t00 = bp[0] * w.x;
    if (mm.y & 2) t10 = bp[1] * w.y;
    if (mm.y & 4) t01 = bp[HW] * w.z;
    if (mm.y & 8) t11 = bp[HW + 1] * w.w;
    outrow[s] = ((t00 + t10) + t01) + t11;
  }
}

// ---------------------------------------------------------------------------
// K5: GEMM layer 1 from transposed A (At[k][m]), C[M][256] row-major.
// 64x64 tile, BK=32, 256 threads, 4x4 acc. (R9-verified, byte-identical.)
// ---------------------------------------------------------------------------
__global__ __launch_bounds__(256) void k_gemm1_At(const float* __restrict__ At,
                                                  const float* __restrict__ W,
                                                  const float* __restrict__ bias,
                                                  float* __restrict__ C) {
  __shared__ __align__(16) float As[32][68];
  __shared__ __align__(16) float Bs[32][68];
  const int bx = blockIdx.x & 3;   // N tile
  const int by = blockIdx.x >> 2;  // M tile
  const int tid = threadIdx.x;
  const int tn = tid & 15, tm = tid >> 4;
  const int m_base = by * 64, n_base = bx * 64;
  float acc[4][4] = {};
  for (int k0 = 0; k0 < CIN; k0 += 32) {
#pragma unroll
    for (int r = 0; r < 2; ++r) {
      int t = tid + r * 256;
      int kk = t >> 4, mg = (t & 15) * 4;
      *(float4*)&As[kk][mg] =
          *(const float4*)&At[(size_t)(k0 + kk) * M_TOT + m_base + mg];
      int row = t >> 3, cg = (t & 7) * 4;
      float4 vw = *(const float4*)&W[(size_t)(n_base + row) * CIN + k0 + cg];
      Bs[cg + 0][row] = vw.x;
      Bs[cg + 1][row] = vw.y;
      Bs[cg + 2][row] = vw.z;
      Bs[cg + 3][row] = vw.w;
    }
    __syncthreads();
#pragma unroll
    for (int kk = 0; kk < 32; ++kk) {
      float4 a4 = *(const float4*)&As[kk][tm * 4];
      float4 b4 = *(const float4*)&Bs[kk][tn * 4];
      float av[4] = {a4.x, a4.y, a4.z, a4.w};
      float bw[4] = {b4.x, b4.y, b4.z, b4.w};
#pragma unroll
      for (int i = 0; i < 4; ++i)
#pragma unroll
        for (int j = 0; j < 4; ++j) acc[i][j] = fmaf(av[i], bw[j], acc[i][j]);
    }
    __syncthreads();
  }
  float bs[4];
#pragma unroll
  for (int j = 0; j < 4; ++j) bs[j] = bias[n_base + tn * 4 + j];
#pragma unroll
  for (int i = 0; i < 4; ++i) {
    float4 o;
    o.x = fmaxf(acc[i][0] + bs[0], 0.0f);
    o.y = fmaxf(acc[i][1] + bs[1], 0.0f);
    o.z = fmaxf(acc[i][2] + bs[2], 0.0f);
    o.w = fmaxf(acc[i][3] + bs[3], 0.0f);
    *(float4*)&C[(size_t)(m_base + tm * 4 + i) * HID + n_base + tn * 4] = o;
  }
}

// ---------------------------------------------------------------------------
// K6: GEMM layer 2 (row-major A). (R9-verified, byte-identical.)
// ---------------------------------------------------------------------------
template <int K>
__global__ __launch_bounds__(256) void k_gemm_relu(const float* __restrict__ A,
                                                   const float* __restrict__ W,
                                                   const float* __restrict__ bias,
                                                   float* __restrict__ C) {
  __shared__ __align__(16) float As[32][68];
  __shared__ __align__(16) float Bs[32][68];
  const int bx = blockIdx.x & 3;
  const int by = blockIdx.x >> 2;
  const int tid = threadIdx.x;
  const int tn = tid & 15, tm = tid >> 4;
  const int m_base = by * 64, n_base = bx * 64;
  float acc[4][4] = {};
  for (int k0 = 0; k0 < K; k0 += 32) {
#pragma unroll
    for (int r = 0; r < 2; ++r) {
      int t = tid + r * 256;
      int row = t >> 3, cg = (t & 7) * 4;
      float4 va = *(const float4*)&A[(size_t)(m_base + row) * K + k0 + cg];
      As[cg + 0][row] = va.x;
      As[cg + 1][row] = va.y;
      As[cg + 2][row] = va.z;
      As[cg + 3][row] = va.w;
      float4 vw = *(const float4*)&W[(size_t)(n_base + row) * K + k0 + cg];
      Bs[cg + 0][row] = vw.x;
      Bs[cg + 1][row] = vw.y;
      Bs[cg + 2][row] = vw.z;
      Bs[cg + 3][row] = vw.w;
    }
    __syncthreads();
#pragma unroll
    for (int kk = 0; kk < 32; ++kk) {
      float4 a4 = *(const float4*)&As[kk][tm * 4];
      float4 b4 = *(const float4*)&Bs[kk][tn * 4];
      float av[4] = {a4.x, a4.y, a4.z, a4.w};
      float bw[4] = {b4.x, b4.y, b4.z, b4.w};
#pragma unroll
      for (int i = 0; i < 4; ++i)
#pragma unroll
        for (int j = 0; j < 4; ++j) acc[i][j] = fmaf(av[i], bw[j], acc[i][j]);
    }
    __syncthreads();
  }
  float bs[4];
#pragma unroll
  for (int j = 0; j < 4; ++j) bs[j] = bias[n_base + tn * 4 + j];
#pragma unroll
  for (int i = 0; i < 4; ++i) {
    float4 o;
    o.x = fmaxf(acc[i][0] + bs[0], 0.0f);
    o.y = fmaxf(acc[i][1] + bs[1], 0.0f);
    o.z = fmaxf(acc[i][2] + bs[2], 0.0f);
    o.w = fmaxf(acc[i][3] + bs[3], 0.0f);
    *(float4*)&C[(size_t)(m_base + tm * 4 + i) * HID + n_base + tn * 4] = o;
  }
}

// ---------------------------------------------------------------------------
// K7: final layer, 4 outputs per point, shuffle reduce; un-permutes sorted
// order on the output scatter (R9-verified, byte-identical).
// ---------------------------------------------------------------------------
__global__ __launch_bounds__(256) void k_out(const float* __restrict__ h,
                                             const float* __restrict__ W3,
                                             const float* __restrict__ b3,
                                             const int* __restrict__ perm,
                                             float* __restrict__ out) {
  int gp = blockIdx.x * 4 + (threadIdx.x >> 6);
  int lane = threadIdx.x & 63;
  const float* hr = h + (size_t)gp * HID;
  float4 hv = *(const float4*)&hr[lane * 4];
  float s[4];
#pragma unroll
  for (int o = 0; o < 4; ++o) {
    float4 w = *(const float4*)&W3[o * HID + lane * 4];
    s[o] = hv.x * w.x + hv.y * w.y + hv.z * w.z + hv.w * w.w;
  }
#pragma unroll
  for (int off = 32; off; off >>= 1)
#pragma unroll
    for (int o = 0; o < 4; ++o) s[o] += __shfl_xor(s[o], off, 64);
  if (lane == 0) {
    int b = gp / NP, ns = gp % NP;
    int n = perm[(size_t)b * NP + ns];
#pragma unroll
    for (int o = 0; o < 4; ++o)
      out[((size_t)b * OUTC + o) * NP + n] = s[o] + b3[o];
  }
}

extern "C" void kernel_launch(void* const* d_in, const int* in_sizes, int n_in,
                              void* d_out, int out_size, void* d_ws, size_t ws_size,
                              hipStream_t stream) {
  const float* fine = (const float*)d_in[0];
  const float* coarse = (const float*)d_in[1];
  const float* logits = (const float*)d_in[2];
  const float* rand_points = (const float*)d_in[3];
  const float* rand_extra = (const float*)d_in[4];
  const float* W1 = (const float*)d_in[5];
  const float* b1 = (const float*)d_in[6];
  const float* W2 = (const float*)d_in[7];
  const float* b2 = (const float*)d_in[8];
  const float* W3 = (const float*)d_in[9];
  const float* b3 = (const float*)d_in[10];
  float* out = (float*)d_out;

  float* out_logits = out;
  float* out_points = out + (size_t)BATCH * OUTC * NP;

  // ws layout (bytes): u | m2s | wtss | perm | featsT | h1 | h2
  char* ws = (char*)d_ws;
  float* u = (float*)(ws + 0);               // 196608
  int2* m2s = (int2*)(ws + 196608);          // 131072
  float4* wtss = (float4*)(ws + 327680);     // 262144
  int* perm = (int*)(ws + 589824);           // 65536
  float* featsT = (float*)(ws + 655360);     // 12582912
  float* h1 = (float*)(ws + 13238272);       // 16777216
  float* h2 = (float*)(ws + 30015488);       // 16777216

  k_uncert_extra<<<(BATCH * NS + BATCH * NR + 255) / 256, 256, 0, stream>>>(
      logits, rand_points, rand_extra, u, out_points);
  k_select<<<BATCH * (NS / 256), 256, 0, stream>>>(u, rand_points, out_points);
  k_meta<<<BATCH, 512, 0, stream>>>(out_points, m2s, wtss, perm);
  k_gather5<<<CIN * BATCH * GCH_SPLIT, 256, 0, stream>>>(fine, coarse, m2s,
                                                         wtss, featsT);
  k_gemm1_At<<<(M_TOT / 64) * 4, 256, 0, stream>>>(featsT, W1, b1, h1);
  k_gemm_relu<HID><<<(M_TOT / 64) * 4, 256, 0, stream>>>(h1, W2, b2, h2);
  k_out<<<M_TOT / 4, 256, 0, stream>>>(h2, W3, b3, perm, out_logits);
}

// Round 13
// 273.356 us; speedup vs baseline: 1.1540x; 1.1002x over previous
//
#include <hip/hip_runtime.h>
#include <math.h>

// Problem constants (from reference)
#define BATCH 4
#define HW 512
#define NPLANE (512 * 512)
#define NS 12288      // oversampled points per batch
#define NU 3072       // top-k uncertain selected
#define NR 1024       // random extra points
#define NP 4096       // total selected points per batch
#define CF_CH 64
#define CC_CH 128
#define CIN 192
#define HID 256
#define OUTC 4
#define M_TOT (BATCH * NP)  // 16384
#define GCH_SPLIT 8         // point-chunks per (batch, channel) in gather

// ---------------------------------------------------------------------------
// Bit-exact replication of XLA:CPU's vectorized f32 expf (Cephes polynomial),
// strict per-op f32 rounding, no FMA. DO NOT TOUCH — top-k order depends on it.
// ---------------------------------------------------------------------------
__device__ __forceinline__ float xla_expf(float xin) {
  float x = fminf(fmaxf(xin, -88.3762626647949f), 88.3762626647950f);
  float fx = floorf(__fadd_rn(__fmul_rn(x, 1.44269504088896341f), 0.5f));
  float tmp = __fmul_rn(0.693359375f, fx);
  float z = __fmul_rn(-2.12194440e-4f, fx);
  x = __fsub_rn(__fsub_rn(x, tmp), z);
  float y = __fadd_rn(__fmul_rn(x, 1.9875691500E-4f), 1.3981999507E-3f);
  y = __fadd_rn(__fmul_rn(y, x), 8.3334519073E-3f);
  y = __fadd_rn(__fmul_rn(y, x), 4.1665795894E-2f);
  y = __fadd_rn(__fmul_rn(y, x), 1.6666665459E-1f);
  y = __fadd_rn(__fmul_rn(y, x), 5.0000001201E-1f);
  z = __fmul_rn(x, x);
  y = __fadd_rn(__fmul_rn(y, z), x);
  y = __fadd_rn(y, 1.0f);
  int n = (int)fx;
  float p2n = __int_as_float((n + 127) << 23);
  return __fmul_rn(y, p2n);
}

// ---------------------------------------------------------------------------
// K1: uncertainty at oversampled points fused with random-extra append
// (R7/R11/R12-verified, byte-identical).
// ---------------------------------------------------------------------------
__global__ void k_uncert_extra(const float* __restrict__ logits,
                               const float* __restrict__ rp,
                               const float* __restrict__ re,
                               float* __restrict__ u,
                               float* __restrict__ pts_out) {
  int gid = blockIdx.x * 256 + threadIdx.x;
  if (gid < BATCH * NS) {
    int b = gid / NS;
    float px = rp[(size_t)gid * 2 + 0];
    float py = rp[(size_t)gid * 2 + 1];
    const float* plane = logits + (size_t)b * OUTC * NPLANE;  // channel 0

    float x = __fsub_rn(__fmul_rn(px, 512.0f), 0.5f);
    float y = __fsub_rn(__fmul_rn(py, 512.0f), 0.5f);
    float x0f = floorf(x), y0f = floorf(y);
    float wx = __fsub_rn(x, x0f);
    float wy = __fsub_rn(y, y0f);
    int x0 = (int)x0f, y0 = (int)y0f;
    int x1 = x0 + 1, y1 = y0 + 1;
    bool vx0 = (x0 >= 0) & (x0 < HW);
    bool vx1 = (x1 >= 0) & (x1 < HW);
    bool vy0 = (y0 >= 0) & (y0 < HW);
    bool vy1 = (y1 >= 0) & (y1 < HW);
    float g00 = (vx0 && vy0) ? plane[y0 * HW + x0] : 0.0f;
    float g10 = (vx1 && vy0) ? plane[y0 * HW + x1] : 0.0f;
    float g01 = (vx0 && vy1) ? plane[y1 * HW + x0] : 0.0f;
    float g11 = (vx1 && vy1) ? plane[y1 * HW + x1] : 0.0f;
    float omx = __fsub_rn(1.0f, wx);
    float omy = __fsub_rn(1.0f, wy);
    float w00 = __fmul_rn(omx, omy);
    float w10 = __fmul_rn(wx, omy);
    float w01 = __fmul_rn(omx, wy);
    float w11 = __fmul_rn(wx, wy);
    float s = __fadd_rn(
        __fadd_rn(__fadd_rn(__fmul_rn(g00, w00), __fmul_rn(g10, w10)),
                  __fmul_rn(g01, w01)),
        __fmul_rn(g11, w11));
    float e = xla_expf(-s);
    float sig = __fdiv_rn(1.0f, __fadd_rn(1.0f, e));
    float t = __fmul_rn(fabsf(__fsub_rn(sig, 0.5f)), 2.0f);
    u[gid] = __fsub_rn(1.0f, t);
  } else {
    int g = gid - BATCH * NS;  // [0, BATCH*NR)
    if (g < BATCH * NR) {
      int b = g / NR, j = g - b * NR;
      pts_out[((size_t)b * NP + NU + j) * 2 + 0] = re[(size_t)g * 2 + 0];
      pts_out[((size_t)b * NP + NU + j) * 2 + 1] = re[(size_t)g * 2 + 1];
    }
  }
}

// ---------------------------------------------------------------------------
// K2: exact stable top-k via ranking (R6-verified, byte-identical). CLOSED.
// ---------------------------------------------------------------------------
__global__ __launch_bounds__(256) void k_select(const float* __restrict__ u,
                                                const float* __restrict__ rp,
                                                float* __restrict__ pts_out) {
  __shared__ __align__(16) float su[NS];
  int b = blockIdx.x / (NS / 256);
  int blk = blockIdx.x % (NS / 256);
  const float* ub = u + (size_t)b * NS;
  for (int t = threadIdx.x; t < NS / 4; t += 256)
    ((float4*)su)[t] = ((const float4*)ub)[t];
  __syncthreads();
  int i = blk * 256 + (int)threadIdx.x;
  int wb = i & ~63;  // wave-uniform (blk*256 is 64-aligned)
  float ui = su[i];
  int r0 = 0, r1 = 0, r2 = 0, r3 = 0;
  for (int j = 0; j < wb; j += 8) {
    float4 v = *(const float4*)&su[j];
    float4 w = *(const float4*)&su[j + 4];
    r0 += (v.x >= ui) + (w.x >= ui);
    r1 += (v.y >= ui) + (w.y >= ui);
    r2 += (v.z >= ui) + (w.z >= ui);
    r3 += (v.w >= ui) + (w.w >= ui);
  }
  for (int j = wb; j < wb + 64; ++j) {
    float vj = su[j];
    r0 += (vj > ui) || (vj == ui && j < i);
  }
  for (int j = wb + 64; j < NS; j += 8) {
    float4 v = *(const float4*)&su[j];
    float4 w = *(const float4*)&su[j + 4];
    r0 += (v.x > ui) + (w.x > ui);
    r1 += (v.y > ui) + (w.y > ui);
    r2 += (v.z > ui) + (w.z > ui);
    r3 += (v.w > ui) + (w.w > ui);
  }
  int rank = (r0 + r1) + (r2 + r3);
  if (rank < NU) {
    pts_out[((size_t)b * NP + rank) * 2 + 0] = rp[((size_t)b * NS + i) * 2 + 0];
    pts_out[((size_t)b * NP + rank) * 2 + 1] = rp[((size_t)b * NS + i) * 2 + 1];
  }
}

// ---------------------------------------------------------------------------
// K3: fused metadata + row-sort + sorted materialization (R12-verified,
// byte-identical).
// ---------------------------------------------------------------------------
__global__ __launch_bounds__(512) void k_meta(const float* __restrict__ pts,
                                              int2* __restrict__ m2s,
                                              float4* __restrict__ wtss,
                                              int* __restrict__ perm) {
  __shared__ int2 marr[NP];  // 32 KB
  __shared__ int hist[512], pref[512];
  int b = blockIdx.x, tid = threadIdx.x;
  hist[tid] = 0;
  __syncthreads();
  float pxr[8], pyr[8];
#pragma unroll
  for (int q = 0; q < 8; ++q) {
    int p = q * 512 + tid;
    float px = pts[((size_t)b * NP + p) * 2 + 0];
    float py = pts[((size_t)b * NP + p) * 2 + 1];
    pxr[q] = px;
    pyr[q] = py;
    float x = px * 512.0f - 0.5f;
    float y = py * 512.0f - 0.5f;
    float x0f = floorf(x), y0f = floorf(y);
    int x0 = (int)x0f, y0 = (int)y0f;
    bool vx0 = (unsigned)x0 < (unsigned)HW;
    bool vx1 = (unsigned)(x0 + 1) < (unsigned)HW;
    bool vy0 = (unsigned)y0 < (unsigned)HW;
    bool vy1 = (unsigned)(y0 + 1) < (unsigned)HW;
    int vm = (int)(vx0 && vy0) | ((int)(vx1 && vy0) << 1) |
             ((int)(vx0 && vy1) << 2) | ((int)(vx1 && vy1) << 3);
    int i00 = y0 * HW + x0;
    marr[p] = make_int2(i00, vm);
    int key = min(max(i00, 0), NPLANE - 1) >> 9;
    atomicAdd(&hist[key], 1);
  }
  __syncthreads();
  int v = hist[tid];
  pref[tid] = v;
  __syncthreads();
  for (int d = 1; d < 512; d <<= 1) {
    int t = (tid >= d) ? pref[tid - d] : 0;
    __syncthreads();
    pref[tid] += t;
    __syncthreads();
  }
  hist[tid] = pref[tid] - v;  // exclusive prefix -> running offsets
  __syncthreads();
#pragma unroll
  for (int q = 0; q < 8; ++q) {
    int p = q * 512 + tid;
    int2 mm = marr[p];
    int key = min(max(mm.x, 0), NPLANE - 1) >> 9;
    int pos = atomicAdd(&hist[key], 1);
    perm[(size_t)b * NP + pos] = p;
    m2s[(size_t)b * NP + pos] = mm;
    float x = pxr[q] * 512.0f - 0.5f;
    float y = pyr[q] * 512.0f - 0.5f;
    float wx = x - floorf(x), wy = y - floorf(y);
    wtss[(size_t)b * NP + pos] =
        make_float4((1.0f - wx) * (1.0f - wy), wx * (1.0f - wy),
                    (1.0f - wx) * wy, wx * wy);
  }
}

// ---------------------------------------------------------------------------
// K4: gather in sorted point order. Interior fast path (vm==15, ~99.2% of
// points): each row pair loaded as one 8-byte memcpy (dwordx2) — halves the
// tap instruction count; window [i00,i00+1] and [i00+HW,i00+HW+1] provably
// in-plane when all 4 taps valid. Boundary points keep the exact scalar
// predicated path. Same lines, same values, same sum order.
// ---------------------------------------------------------------------------
__global__ __launch_bounds__(256) void k_gather6(
    const float* __restrict__ fine, const float* __restrict__ coarse,
    const int2* __restrict__ m2s, const float4* __restrict__ wtss,
    float* __restrict__ featsT) {
  int c = blockIdx.x % CIN;
  int rem = blockIdx.x / CIN;
  int b = rem & (BATCH - 1);
  int part = rem >> 2;
  const float* plane = (c < CF_CH)
                           ? fine + ((size_t)b * CF_CH + c) * NPLANE
                           : coarse + ((size_t)b * CC_CH + (c - CF_CH)) * NPLANE;
  const int2* m2b = m2s + (size_t)b * NP;
  const float4* wtsb = wtss + (size_t)b * NP;
  float* outrow = featsT + (size_t)c * M_TOT + (size_t)b * NP;
  int s0 = part * (NP / GCH_SPLIT);
#pragma unroll
  for (int q = 0; q < NP / GCH_SPLIT / 256; ++q) {
    int s = s0 + q * 256 + (int)threadIdx.x;
    int2 mm = m2b[s];
    float4 w = wtsb[s];
    float r;
    if (mm.y == 15) {
      float2 ra, rb;
      __builtin_memcpy(&ra, &plane[mm.x], 8);
      __builtin_memcpy(&rb, &plane[mm.x + HW], 8);
      r = (((ra.x * w.x) + (ra.y * w.y)) + (rb.x * w.z)) + (rb.y * w.w);
    } else {
      const float* bp = plane + mm.x;
      float t00 = 0.0f, t10 = 0.0f, t01 = 0.0f, t11 = 0.0f;
      if (mm.y & 1) t00 = bp[0] * w.x;
      if (mm.y & 2) t10 = bp[1] * w.y;
      if (mm.y & 4) t01 = bp[HW] * w.z;
      if (mm.y & 8) t11 = bp[HW + 1] * w.w;
      r = ((t00 + t10) + t01) + t11;
    }
    outrow[s] = r;
  }
}

// ---------------------------------------------------------------------------
// K5: GEMM layer 1 from transposed A (At[k][m]), C[M][256] row-major.
// 128x64 tile, BK=32, 256 threads, 8x4 acc (32 FMA per 3 ds_read_b128).
// k-summation order per output element identical to the 64x64 version ->
// bit-identical results.
// ---------------------------------------------------------------------------
__global__ __launch_bounds__(256) void k_gemm1_At(const float* __restrict__ At,
                                                  const float* __restrict__ W,
                                                  const float* __restrict__ bias,
                                                  float* __restrict__ C) {
  __shared__ __align__(16) float As[32][132];
  __shared__ __align__(16) float Bs[32][68];
  const int bx = blockIdx.x & 3;   // N tile (256/64)
  const int by = blockIdx.x >> 2;  // M tile (16384/128)
  const int tid = threadIdx.x;
  const int tn = tid & 15, tm = tid >> 4;
  const int m_base = by * 128, n_base = bx * 64;
  float acc[8][4] = {};
  for (int k0 = 0; k0 < CIN; k0 += 32) {
#pragma unroll
    for (int r = 0; r < 4; ++r) {  // A: 32k x 128m = 1024 float4
      int t = tid + r * 256;
      int kk = t >> 5, mg = (t & 31) * 4;
      *(float4*)&As[kk][mg] =
          *(const float4*)&At[(size_t)(k0 + kk) * M_TOT + m_base + mg];
    }
#pragma unroll
    for (int r = 0; r < 2; ++r) {  // B: 64n x 32k
      int t = tid + r * 256;
      int row = t >> 3, cg = (t & 7) * 4;
      float4 vw = *(const float4*)&W[(size_t)(n_base + row) * CIN + k0 + cg];
      Bs[cg + 0][row] = vw.x;
      Bs[cg + 1][row] = vw.y;
      Bs[cg + 2][row] = vw.z;
      Bs[cg + 3][row] = vw.w;
    }
    __syncthreads();
#pragma unroll
    for (int kk = 0; kk < 32; ++kk) {
      float a[8];
      *(float4*)&a[0] = *(const float4*)&As[kk][tm * 8];
      *(float4*)&a[4] = *(const float4*)&As[kk][tm * 8 + 4];
      float4 b4 = *(const float4*)&Bs[kk][tn * 4];
      float bw[4] = {b4.x, b4.y, b4.z, b4.w};
#pragma unroll
      for (int i = 0; i < 8; ++i)
#pragma unroll
        for (int j = 0; j < 4; ++j) acc[i][j] = fmaf(a[i], bw[j], acc[i][j]);
    }
    __syncthreads();
  }
  float bs[4];
#pragma unroll
  for (int j = 0; j < 4; ++j) bs[j] = bias[n_base + tn * 4 + j];
#pragma unroll
  for (int i = 0; i < 8; ++i) {
    float4 o;
    o.x = fmaxf(acc[i][0] + bs[0], 0.0f);
    o.y = fmaxf(acc[i][1] + bs[1], 0.0f);
    o.z = fmaxf(acc[i][2] + bs[2], 0.0f);
    o.w = fmaxf(acc[i][3] + bs[3], 0.0f);
    *(float4*)&C[(size_t)(m_base + tm * 8 + i) * HID + n_base + tn * 4] = o;
  }
}

// ---------------------------------------------------------------------------
// K6: GEMM layer 2 (row-major A), 128x64 tile, 8x4 acc. Bit-identical
// k-order per output.
// ---------------------------------------------------------------------------
template <int K>
__global__ __launch_bounds__(256) void k_gemm_relu(const float* __restrict__ A,
                                                   const float* __restrict__ W,
                                                   const float* __restrict__ bias,
                                                   float* __restrict__ C) {
  __shared__ __align__(16) float As[32][132];
  __shared__ __align__(16) float Bs[32][68];
  const int bx = blockIdx.x & 3;
  const int by = blockIdx.x >> 2;
  const int tid = threadIdx.x;
  const int tn = tid & 15, tm = tid >> 4;
  const int m_base = by * 128, n_base = bx * 64;
  float acc[8][4] = {};
  for (int k0 = 0; k0 < K; k0 += 32) {
#pragma unroll
    for (int r = 0; r < 4; ++r) {  // A: 128 rows x 32 k
      int t = tid + r * 256;
      int row = t >> 3, cg = (t & 7) * 4;
      float4 va = *(const float4*)&A[(size_t)(m_base + row) * K + k0 + cg];
      As[cg + 0][row] = va.x;
      As[cg + 1][row] = va.y;
      As[cg + 2][row] = va.z;
      As[cg + 3][row] = va.w;
    }
#pragma unroll
    for (int r = 0; r < 2; ++r) {  // B: 64n x 32k
      int t = tid + r * 256;
      int row = t >> 3, cg = (t & 7) * 4;
      float4 vw = *(const float4*)&W[(size_t)(n_base + row) * K + k0 + cg];
      Bs[cg + 0][row] = vw.x;
      Bs[cg + 1][row] = vw.y;
      Bs[cg + 2][row] = vw.z;
      Bs[cg + 3][row] = vw.w;
    }
    __syncthreads();
#pragma unroll
    for (int kk = 0; kk < 32; ++kk) {
      float a[8];
      *(float4*)&a[0] = *(const float4*)&As[kk][tm * 8];
      *(float4*)&a[4] = *(const float4*)&As[kk][tm * 8 + 4];
      float4 b4 = *(const float4*)&Bs[kk][tn * 4];
      float bw[4] = {b4.x, b4.y, b4.z, b4.w};
#pragma unroll
      for (int i = 0; i < 8; ++i)
#pragma unroll
        for (int j = 0; j < 4; ++j) acc[i][j] = fmaf(a[i], bw[j], acc[i][j]);
    }
    __syncthreads();
  }
  float bs[4];
#pragma unroll
  for (int j = 0; j < 4; ++j) bs[j] = bias[n_base + tn * 4 + j];
#pragma unroll
  for (int i = 0; i < 8; ++i) {
    float4 o;
    o.x = fmaxf(acc[i][0] + bs[0], 0.0f);
    o.y = fmaxf(acc[i][1] + bs[1], 0.0f);
    o.z = fmaxf(acc[i][2] + bs[2], 0.0f);
    o.w = fmaxf(acc[i][3] + bs[3], 0.0f);
    *(float4*)&C[(size_t)(m_base + tm * 8 + i) * HID + n_base + tn * 4] = o;
  }
}

// ---------------------------------------------------------------------------
// K7: final layer, 4 outputs per point, shuffle reduce; un-permutes sorted
// order on the output scatter (R9/R12-verified, byte-identical).
// ---------------------------------------------------------------------------
__global__ __launch_bounds__(256) void k_out(const float* __restrict__ h,
                                             const float* __restrict__ W3,
                                             const float* __restrict__ b3,
                                             const int* __restrict__ perm,
                                             float* __restrict__ out) {
  int gp = blockIdx.x * 4 + (threadIdx.x >> 6);
  int lane = threadIdx.x & 63;
  const float* hr = h + (size_t)gp * HID;
  float4 hv = *(const float4*)&hr[lane * 4];
  float s[4];
#pragma unroll
  for (int o = 0; o < 4; ++o) {
    float4 w = *(const float4*)&W3[o * HID + lane * 4];
    s[o] = hv.x * w.x + hv.y * w.y + hv.z * w.z + hv.w * w.w;
  }
#pragma unroll
  for (int off = 32; off; off >>= 1)
#pragma unroll
    for (int o = 0; o < 4; ++o) s[o] += __shfl_xor(s[o], off, 64);
  if (lane == 0) {
    int b = gp / NP, ns = gp % NP;
    int n = perm[(size_t)b * NP + ns];
#pragma unroll
    for (int o = 0; o < 4; ++o)
      out[((size_t)b * OUTC + o) * NP + n] = s[o] + b3[o];
  }
}

extern "C" void kernel_launch(void* const* d_in, const int* in_sizes, int n_in,
                              void* d_out, int out_size, void* d_ws, size_t ws_size,
                              hipStream_t stream) {
  const float* fine = (const float*)d_in[0];
  const float* coarse = (const float*)d_in[1];
  const float* logits = (const float*)d_in[2];
  const float* rand_points = (const float*)d_in[3];
  const float* rand_extra = (const float*)d_in[4];
  const float* W1 = (const float*)d_in[5];
  const float* b1 = (const float*)d_in[6];
  const float* W2 = (const float*)d_in[7];
  const float* b2 = (const float*)d_in[8];
  const float* W3 = (const float*)d_in[9];
  const float* b3 = (const float*)d_in[10];
  float* out = (float*)d_out;

  float* out_logits = out;
  float* out_points = out + (size_t)BATCH * OUTC * NP;

  // ws layout (bytes): u | m2s | wtss | perm | featsT | h1 | h2
  char* ws = (char*)d_ws;
  float* u = (float*)(ws + 0);               // 196608
  int2* m2s = (int2*)(ws + 196608);          // 131072
  float4* wtss = (float4*)(ws + 327680);     // 262144
  int* perm = (int*)(ws + 589824);           // 65536
  float* featsT = (float*)(ws + 655360);     // 12582912
  float* h1 = (float*)(ws + 13238272);       // 16777216
  float* h2 = (float*)(ws + 30015488);       // 16777216

  k_uncert_extra<<<(BATCH * NS + BATCH * NR + 255) / 256, 256, 0, stream>>>(
      logits, rand_points, rand_extra, u, out_points);
  k_select<<<BATCH * (NS / 256), 256, 0, stream>>>(u, rand_points, out_points);
  k_meta<<<BATCH, 512, 0, stream>>>(out_points, m2s, wtss, perm);
  k_gather6<<<CIN * BATCH * GCH_SPLIT, 256, 0, stream>>>(fine, coarse, m2s,
                                                         wtss, featsT);
  k_gemm1_At<<<(M_TOT / 128) * 4, 256, 0, stream>>>(featsT, W1, b1, h1);
  k_gemm_relu<HID><<<(M_TOT / 128) * 4, 256, 0, stream>>>(h1, W2, b2, h2);
  k_out<<<M_TOT / 4, 256, 0, stream>>>(h2, W3, b3, perm, out_logits);
}